// Round 3
// baseline (171.036 us; speedup 1.0000x reference)
//
#include <hip/hip_runtime.h>
#include <stdint.h>

#define NB 1024
#define BB 256
#define KK 16
#define HH 64
#define WW 64
#define F_FULL 144
#define HDIM 128
#define CDIM 16
#define KPAD 160
#define APITCH 168   // A LDS pitch (bf16 elems)
#define HPITCH 136   // h LDS pitch (bf16 elems)

typedef __bf16 bf16x8 __attribute__((ext_vector_type(8)));
typedef float f32x4 __attribute__((ext_vector_type(4)));

// ---------------- ws layout ----------------
// [0,4)        : int err_count
// [256, ..)    : W1t bf16 [16][128][160]  (drop-shifted, h-major, k-contig, k>=144 zero)
// [.., ..)     : W2b bf16 [16][128]       (c-major, k-contig)
// [.., ..)     : zt u8 (H,W,B,K)
#define W1T_OFF 256
#define W1T_BYTES (16 * HDIM * KPAD * 2)
#define W2B_OFF (W1T_OFF + W1T_BYTES)
#define W2B_BYTES (CDIM * HDIM * 2)
#define ZT_OFF (W2B_OFF + W2B_BYTES)

__device__ __forceinline__ unsigned short bf16_bits(float v) {
    __bf16 b = (__bf16)v;
    return __builtin_bit_cast(unsigned short, b);
}

// Fused prep: W1t (blocks 0..1279), W2b + err zero (blocks 1280..1287)
__global__ void prep_kernel(const float* __restrict__ W1, const float* __restrict__ W2,
                            unsigned short* __restrict__ W1t, unsigned short* __restrict__ W2b,
                            int* __restrict__ err_count) {
    int bid = blockIdx.x;
    int t = threadIdx.x;
    if (bid < 1280) {
        int idx = bid * 256 + t;            // 16*128*160 = 327680
        int k = idx % KPAD;
        int h = (idx / KPAD) % HDIM;
        int s = idx / (KPAD * HDIM);
        int drop = 4 * KK + s;
        float val = 0.0f;
        if (k < F_FULL && k != drop) {
            int src = k - (k > drop ? 1 : 0);
            val = W1[src * HDIM + h];
        }
        W1t[idx] = bf16_bits(val);
    } else {
        int idx = (bid - 1280) * 256 + t;   // 2048 total
        if (idx < CDIM * HDIM) {
            int k = idx % HDIM;
            int c = idx / HDIM;
            W2b[idx] = bf16_bits(W2[k * CDIM + c]);
        }
        if (bid == 1280 && t == 0) *err_count = 0;
    }
}

// Transpose z (B,K,H,W) int32 -> zt u8 (H,W,B,K).
// As 4096x4096: In[r=b*16+k][c=h*64+w] -> Out[c][r]. Tile: 128 r x 32 c.
#define TP 144
__global__ __launch_bounds__(256) void transpose_kernel(const int* __restrict__ z,
                                                        uint8_t* __restrict__ zt) {
    __shared__ uint8_t tile[32 * TP];   // tile[c][r], pitch 144 (16B-aligned rows)
    int t = threadIdx.x;
    int bx = blockIdx.x & 127;          // c tile
    int by = blockIdx.x >> 7;           // r tile, 0..31
    int c0 = bx * 32, r0 = by * 128;
#pragma unroll
    for (int i = 0; i < 4; ++i) {
        int lin = i * 256 + t;          // 1024 uchar4 groups
        int c = lin & 31;
        int rq = lin >> 5;              // 0..31 -> rows rq*4..rq*4+3
        uchar4 v;
        v.x = (uint8_t)z[(size_t)(r0 + rq * 4 + 0) * 4096 + c0 + c];
        v.y = (uint8_t)z[(size_t)(r0 + rq * 4 + 1) * 4096 + c0 + c];
        v.z = (uint8_t)z[(size_t)(r0 + rq * 4 + 2) * 4096 + c0 + c];
        v.w = (uint8_t)z[(size_t)(r0 + rq * 4 + 3) * 4096 + c0 + c];
        *(uchar4*)(tile + c * TP + rq * 4) = v;
    }
    __syncthreads();
    int cy = t >> 3, rx = t & 7;        // 32 c-rows x 8 x 16B = full 32x128 tile
    uint4 v = *(const uint4*)(tile + cy * TP + rx * 16);
    *(uint4*)(zt + (size_t)(c0 + cy) * 4096 + r0 + rx * 16) = v;
}

// Main fused MFMA kernel: one block = (n, 64-wide b tile), 4 waves.
// LDS overlay: sA [64][168] bf16 (21504 B) / sH [64][136] bf16 (17408 B, same base)
//              slg [64][17] f32 at byte 17408 (disjoint from sH) -> total 21760 B
__global__ __launch_bounds__(256, 6) void main_kernel(
    const uint8_t* __restrict__ zt, const unsigned short* __restrict__ W1t,
    const float* __restrict__ b1, const unsigned short* __restrict__ W2b,
    const float* __restrict__ b2, const int* __restrict__ bs,
    const int* __restrict__ ii, const int* __restrict__ jj,
    int* __restrict__ err_count) {
    __shared__ __align__(16) unsigned char smem[21760];
    unsigned short* sA = (unsigned short*)smem;           // [64][APITCH]
    unsigned short* sH = (unsigned short*)smem;           // [64][HPITCH]
    float* slg = (float*)(smem + 64 * HPITCH * 2);        // [64][17]

    int t = threadIdx.x;
    int bid = blockIdx.x;
    int n = bid >> 2;
    int b_base = (bid & 3) << 6;
    int wave = t >> 6, lane = t & 63;
    int l15 = lane & 15, l4 = lane >> 4;

    int in_ = ii[n], jn = jj[n], sn = bs[n];

    // ---- zero A pad region k in [144,168) ----
    if (t < 192) {
        int b = t / 3, part = t % 3;
        *(uint4*)(sA + b * APITCH + F_FULL + part * 8) = make_uint4(0, 0, 0, 0);
    }

    // ---- B fragments (registers, L2-hot global loads) ----
    const unsigned short* w1s = W1t + (size_t)sn * (HDIM * KPAD);
    int n0 = wave * 32;
    bf16x8 Bf[2][5];
#pragma unroll
    for (int nt = 0; nt < 2; ++nt)
#pragma unroll
        for (int ks = 0; ks < 5; ++ks)
            Bf[nt][ks] = *(const bf16x8*)(w1s + (n0 + nt * 16 + l15) * KPAD + ks * 32 + l4 * 8);
    bf16x8 Bf2[4];
#pragma unroll
    for (int ks = 0; ks < 4; ++ks)
        Bf2[ks] = *(const bf16x8*)(W2b + l15 * HDIM + ks * 32 + l4 * 8);
    float b1v0 = b1[n0 + l15], b1v1 = b1[n0 + 16 + l15];
    float b2v = b2[l15];

    // ---- stage ctx -> sA bf16: 9 pixels x 64 b x 16 k ----
    for (int item = t; item < 9 * 64; item += 256) {
        int p = item >> 6;
        int b = item & 63;
        int di = p / 3 - 1, dj = p % 3 - 1;
        int ni = (in_ + di + HH) & (HH - 1);
        int nj = (jn + dj + WW) & (WW - 1);
        const uint8_t* src = zt + (((size_t)(ni * WW + nj) * BB + (b_base + b)) << 4);
        uint4 raw = *(const uint4*)src;
        const uint8_t* bytes = (const uint8_t*)&raw;
        union { __bf16 h[16]; uint4 q[2]; } u;
#pragma unroll
        for (int k = 0; k < 16; ++k)
            u.h[k] = (__bf16)((float)bytes[k] * (1.0f / 15.0f));
        uint4* dst = (uint4*)(sA + b * APITCH + p * 16);
        dst[0] = u.q[0];
        dst[1] = u.q[1];
    }
    __syncthreads();

    // ---- GEMM1: M=64 x N=128 x K=160, wave owns 32 N-cols, 4 M-tiles ----
    f32x4 acc[4][2] = {};
#pragma unroll
    for (int mt = 0; mt < 4; ++mt) {
        bf16x8 Af[5];
#pragma unroll
        for (int ks = 0; ks < 5; ++ks)
            Af[ks] = *(const bf16x8*)(sA + (mt * 16 + l15) * APITCH + ks * 32 + l4 * 8);
#pragma unroll
        for (int ks = 0; ks < 5; ++ks) {
            acc[mt][0] = __builtin_amdgcn_mfma_f32_16x16x32_bf16(Af[ks], Bf[0][ks], acc[mt][0], 0, 0, 0);
            acc[mt][1] = __builtin_amdgcn_mfma_f32_16x16x32_bf16(Af[ks], Bf[1][ks], acc[mt][1], 0, 0, 0);
        }
    }
    __syncthreads();   // all sA reads done before sH overlay writes

    // ---- bias + relu -> sH bf16 [b][h] ----
#pragma unroll
    for (int mt = 0; mt < 4; ++mt)
#pragma unroll
        for (int nt = 0; nt < 2; ++nt) {
            float bv = nt ? b1v1 : b1v0;
            int hcol = n0 + nt * 16 + l15;
#pragma unroll
            for (int r = 0; r < 4; ++r) {
                int b = mt * 16 + l4 * 4 + r;
                float v = fmaxf(acc[mt][nt][r] + bv, 0.0f);
                sH[b * HPITCH + hcol] = bf16_bits(v);
            }
        }
    __syncthreads();

    // ---- GEMM2: M=64 x N=16 x K=128; wave owns M-tile `wave` ----
    f32x4 acc2 = {};
#pragma unroll
    for (int ks = 0; ks < 4; ++ks) {
        bf16x8 Af = *(const bf16x8*)(sH + (wave * 16 + l15) * HPITCH + ks * 32 + l4 * 8);
        acc2 = __builtin_amdgcn_mfma_f32_16x16x32_bf16(Af, Bf2[ks], acc2, 0, 0, 0);
    }
#pragma unroll
    for (int r = 0; r < 4; ++r) {
        int b = wave * 16 + l4 * 4 + r;
        slg[b * 17 + l15] = acc2[r] + b2v;
    }
    __syncthreads();

    // ---- argmax + compare + ballot (wave 0) ----
    if (t < 64) {
        float best = slg[t * 17];
        int pi = 0;
#pragma unroll
        for (int c = 1; c < CDIM; ++c) {
            float v = slg[t * 17 + c];
            if (v > best) { best = v; pi = c; }   // strict > = first-max (jnp.argmax)
        }
        int tgt = zt[(((size_t)(in_ * WW + jn) * BB + b_base + t) << 4) + sn];
        unsigned long long m = __ballot(pi != tgt);
        if (t == 0) atomicAdd(err_count, (int)__popcll(m));
    }
}

__global__ void finalize_kernel(const int* __restrict__ err_count, float* __restrict__ out) {
    out[0] = (float)(*err_count) / (float)(NB * BB);
}

extern "C" void kernel_launch(void* const* d_in, const int* in_sizes, int n_in,
                              void* d_out, int out_size, void* d_ws, size_t ws_size,
                              hipStream_t stream) {
    const int* z = (const int*)d_in[0];
    const int* bs = (const int*)d_in[1];
    const int* ii = (const int*)d_in[2];
    const int* jj = (const int*)d_in[3];
    const float* W1 = (const float*)d_in[4];
    const float* b1 = (const float*)d_in[5];
    const float* W2 = (const float*)d_in[6];
    const float* b2 = (const float*)d_in[7];
    float* out = (float*)d_out;

    uint8_t* ws = (uint8_t*)d_ws;
    int* err_count = (int*)ws;
    unsigned short* W1t = (unsigned short*)(ws + W1T_OFF);
    unsigned short* W2b = (unsigned short*)(ws + W2B_OFF);
    uint8_t* zt = ws + ZT_OFF;

    prep_kernel<<<1288, 256, 0, stream>>>(W1, W2, W1t, W2b, err_count);
    transpose_kernel<<<128 * 32, 256, 0, stream>>>(z, zt);
    main_kernel<<<NB * 4, 256, 0, stream>>>(zt, W1t, b1, W2b, b2, bs, ii, jj, err_count);
    finalize_kernel<<<1, 1, 0, stream>>>(err_count, out);
}